// Round 1
// 1438.530 us; speedup vs baseline: 1.1039x; 1.1039x over previous
//
#include <hip/hip_runtime.h>
#include <stdint.h>

#define TOKENS 32768
#define HIDDEN 2048
#define INTER  1408
#define NEXP   16

typedef unsigned short u16;
typedef __bf16 bf16x8  __attribute__((ext_vector_type(8)));
typedef float  floatx16 __attribute__((ext_vector_type(16)));
typedef unsigned short u16x8 __attribute__((ext_vector_type(8)));

// async global->LDS, 16B per lane; LDS dest = wave-uniform base + lane*16
#define GLOAD_LDS(g, l) __builtin_amdgcn_global_load_lds( \
    (const __attribute__((address_space(1))) void*)(g),    \
    (__attribute__((address_space(3))) void*)(l), 16, 0, 0)

__device__ __forceinline__ u16 f2bf(float f) {
    uint32_t u = __builtin_bit_cast(uint32_t, f);
    u = (u + 0x7FFFu + ((u >> 16) & 1u)) >> 16;   // round-to-nearest-even
    return (u16)u;
}

// ---------------- elementwise fp32 -> bf16 (x) ----------------
__global__ void convert_x(const float* __restrict__ src, u16* __restrict__ dst) {
    int idx = blockIdx.x * blockDim.x + threadIdx.x;   // one float4 per thread
    float4 v = ((const float4*)src)[idx];
    ushort4 o;
    o.x = f2bf(v.x); o.y = f2bf(v.y); o.z = f2bf(v.z); o.w = f2bf(v.w);
    ((ushort4*)dst)[idx] = o;
}

// ------- transpose+convert, vectorized: fp32 [E][R][C] -> bf16 [E][C][R] -------
// 64x64 tile, 256 threads: float4 loads, register 4x4 transpose, LDS holds the
// TRANSPOSED bf16 tile so phase-2 reads/writes are fully vectorized.
__global__ void transpose_cvt(const float* __restrict__ src, u16* __restrict__ dst,
                              int R, int C) {
    __shared__ __align__(16) u16 tl[64][72];   // [c][r], stride 144B
    const int e  = blockIdx.z;
    const float* s = src + (size_t)e * R * C;
    u16*         d = dst + (size_t)e * R * C;
    const int r0 = blockIdx.y * 64, c0 = blockIdx.x * 64;
    const int tid = threadIdx.x;
    const int c4 = (tid & 15) * 4;     // 4-col group
    const int rq = tid >> 4;           // 4-row quad, 0..15
    float m[4][4];
#pragma unroll
    for (int k = 0; k < 4; ++k) {
        float4 v = *(const float4*)(s + (size_t)(r0 + rq * 4 + k) * C + (c0 + c4));
        m[k][0] = v.x; m[k][1] = v.y; m[k][2] = v.z; m[k][3] = v.w;
    }
#pragma unroll
    for (int j = 0; j < 4; ++j) {
        ushort4 o;
        o.x = f2bf(m[0][j]); o.y = f2bf(m[1][j]); o.z = f2bf(m[2][j]); o.w = f2bf(m[3][j]);
        *(ushort4*)&tl[c4 + j][rq * 4] = o;    // 8B-aligned (144*c + 8*rq)
    }
    __syncthreads();
#pragma unroll
    for (int p = 0; p < 2; ++p) {
        int q  = p * 256 + tid;
        int oc = q >> 3;               // 0..63 output row (C index)
        int r8 = (q & 7) * 8;          // 16B chunk along R
        u16x8 w = *(const u16x8*)&tl[oc][r8];
        *(u16x8*)(d + (size_t)(c0 + oc) * R + (r0 + r8)) = w;
    }
}

// ---------------- fused gate+up GEMM + SwiGLU -> h (bf16) ----------------
// 128x128 tile, BK=32, double-buffered LDS + 2-phase prefetch, XOR seg-swizzle.
// LDS dest is linear (global_load_lds requirement); the swizzle is applied by
// permuting the per-lane GLOBAL source k-segment and the ds_read address (G21).
__global__ __launch_bounds__(256, 2)
void gemm_gateup(const u16* __restrict__ xb, const u16* __restrict__ wgb,
                 const u16* __restrict__ wub, const int* __restrict__ gsz,
                 u16* __restrict__ hbuf) {
    __shared__ __align__(16) u16 smem[2 * 3 * 128 * 32];   // 48 KiB

    const int tid  = threadIdx.x;
    const int wave = tid >> 6;
    const int lane = tid & 63;

    // expert-aligned XCD chunking: XCD = id&7 owns rows [xcd*32, xcd*32+32) (2 experts),
    // inner order: 4 supertiles of 8 rows, each sweeping all 11 col-blocks.
    const int id  = blockIdx.x;              // 0..2815
    const int xcd = id & 7;
    const int t   = id >> 3;                 // 0..351
    const int sub = t / 88;                  // 8-row supertile
    const int rem = t - sub * 88;
    const int yc  = rem >> 3;                // col-block 0..10
    const int r8  = rem & 7;
    const int row0 = (xcd * 32 + sub * 8 + r8) * 128;
    const int col0 = yc * 128;

    int e = 0, cum = 0;
    for (int i = 0; i < NEXP; ++i) {
        int sgl = gsz[i];
        if (row0 >= cum + sgl) cum += sgl; else { e = i; break; }
    }

    // staging: per tile 512 16B-segments; lane handles segs s0 and s0+64.
    // seg s = row m * 4 + j; data stored there comes from k-seg c = j ^ ((m>>1)&3).
    const int s0 = wave * 128 + lane;
    const int m0 = s0 >> 2;
    const int m1 = m0 + 16;                          // seg s0+64; same swizzle key
    const int ck = (s0 & 3) ^ ((m0 >> 1) & 3);
    const int ka = ck * 8;

    const u16* pA0 = xb + (size_t)(row0 + m0) * HIDDEN + ka;
    const u16* pA1 = xb + (size_t)(row0 + m1) * HIDDEN + ka;
    const size_t wb = (size_t)e * INTER + col0;
    const u16* pG0 = wgb + (wb + m0) * HIDDEN + ka;
    const u16* pG1 = wgb + (wb + m1) * HIDDEN + ka;
    const u16* pU0 = wub + (wb + m0) * HIDDEN + ka;
    const u16* pU1 = wub + (wb + m1) * HIDDEN + ka;

    const int ldsW = wave * 1024;            // wave-uniform LDS dest base (u16)

    const int wm = (wave >> 1) * 64;
    const int wn = (wave & 1) * 64;
    const int lm = lane & 31;
    const int hi = lane >> 5;
    const int key = (lm >> 1) & 3;           // (row>>1)&3 for row = 32k + lm
    const int sw0 = ((0 + hi) ^ key) * 8;    // ks=0: k-seg = hi
    const int sw1 = ((2 + hi) ^ key) * 8;    // ks=1: k-seg = 2+hi

    floatx16 ag[2][2], au[2][2];
#pragma unroll
    for (int i = 0; i < 2; ++i)
#pragma unroll
        for (int j = 0; j < 2; ++j)
#pragma unroll
            for (int r = 0; r < 16; ++r) { ag[i][j][r] = 0.f; au[i][j][r] = 0.f; }

#define STAGE_GU(B) do { u16* _s = smem + (B) * 12288 + ldsW;                 \
        GLOAD_LDS(pA0, _s);        GLOAD_LDS(pA1, _s + 512);                  \
        GLOAD_LDS(pG0, _s + 4096); GLOAD_LDS(pG1, _s + 4608);                 \
        GLOAD_LDS(pU0, _s + 8192); GLOAD_LDS(pU1, _s + 8704);                 \
        pA0 += 32; pA1 += 32; pG0 += 32; pG1 += 32; pU0 += 32; pU1 += 32; } while (0)

#define COMPUTE_GU(B) do {                                                    \
        const u16* _A = smem + (B) * 12288;                                   \
        const u16* _G = _A + 4096;                                            \
        const u16* _U = _A + 8192;                                            \
        _Pragma("unroll")                                                     \
        for (int ks = 0; ks < 2; ++ks) {                                      \
            const int sw = ks ? sw1 : sw0;                                    \
            bf16x8 a[2], bg[2], bu[2];                                        \
            _Pragma("unroll")                                                 \
            for (int i = 0; i < 2; ++i) {                                     \
                a[i]  = *(const bf16x8*)(_A + (wm + i * 32 + lm) * 32 + sw);  \
                bg[i] = *(const bf16x8*)(_G + (wn + i * 32 + lm) * 32 + sw);  \
                bu[i] = *(const bf16x8*)(_U + (wn + i * 32 + lm) * 32 + sw);  \
            }                                                                 \
            _Pragma("unroll")                                                 \
            for (int i = 0; i < 2; ++i)                                       \
                _Pragma("unroll")                                             \
                for (int j = 0; j < 2; ++j) {                                 \
                    ag[i][j] = __builtin_amdgcn_mfma_f32_32x32x16_bf16(a[i], bg[j], ag[i][j], 0, 0, 0); \
                    au[i][j] = __builtin_amdgcn_mfma_f32_32x32x16_bf16(a[i], bu[j], au[i][j], 0, 0, 0); \
                }                                                             \
        } } while (0)

    STAGE_GU(0);
    __syncthreads();                         // tile 0 resident
#pragma unroll 1
    for (int it = 0; it < HIDDEN / 32; it += 2) {
        STAGE_GU(1);                         // prefetch tile it+1 (in flight over compute)
        COMPUTE_GU(0);                       // tile it
        __syncthreads();                     // drains vmcnt + barrier
        if (it + 2 < HIDDEN / 32) STAGE_GU(0);
        COMPUTE_GU(1);                       // tile it+1
        __syncthreads();
    }
#undef STAGE_GU
#undef COMPUTE_GU

    // epilogue: silu(gate)*up -> bf16 h.  C/D: col=lane&31, row=(r&3)+8*(r>>2)+4*(lane>>5)
    const int rb = 4 * hi;
#pragma unroll
    for (int i = 0; i < 2; ++i)
#pragma unroll
        for (int j = 0; j < 2; ++j)
#pragma unroll
            for (int r = 0; r < 16; ++r) {
                int rr = wm + i * 32 + rb + (r & 3) + 8 * (r >> 2);
                int cc = wn + j * 32 + lm;
                float g = ag[i][j][r], u = au[i][j][r];
                float h = (g / (1.f + __expf(-g))) * u;
                hbuf[(size_t)(row0 + rr) * INTER + (col0 + cc)] = f2bf(h);
            }
}

// ---------------- down GEMM: out = h @ w_down (fp32 out) ----------------
__global__ __launch_bounds__(256, 2)
void gemm_down(const u16* __restrict__ hbuf, const u16* __restrict__ wdb,
               const int* __restrict__ gsz, float* __restrict__ out) {
    __shared__ __align__(16) u16 smem[2 * 2 * 128 * 32];   // 32 KiB

    const int tid  = threadIdx.x;
    const int wave = tid >> 6;
    const int lane = tid & 63;

    // expert-aligned XCD chunking (16 col-blocks)
    const int id  = blockIdx.x;              // 0..4095
    const int xcd = id & 7;
    const int t   = id >> 3;                 // 0..511
    const int sub = t >> 7;                  // /(16*8)
    const int rem = t & 127;
    const int yc  = rem >> 3;
    const int r8  = rem & 7;
    const int row0 = (xcd * 32 + sub * 8 + r8) * 128;
    const int col0 = yc * 128;

    int e = 0, cum = 0;
    for (int i = 0; i < NEXP; ++i) {
        int sgl = gsz[i];
        if (row0 >= cum + sgl) cum += sgl; else { e = i; break; }
    }

    const int s0 = wave * 128 + lane;
    const int m0 = s0 >> 2;
    const int m1 = m0 + 16;
    const int ck = (s0 & 3) ^ ((m0 >> 1) & 3);
    const int ka = ck * 8;

    const u16* pA0 = hbuf + (size_t)(row0 + m0) * INTER + ka;
    const u16* pA1 = hbuf + (size_t)(row0 + m1) * INTER + ka;
    const size_t wb = (size_t)e * HIDDEN + col0;
    const u16* pB0 = wdb + (wb + m0) * INTER + ka;
    const u16* pB1 = wdb + (wb + m1) * INTER + ka;

    const int ldsW = wave * 1024;

    const int wm = (wave >> 1) * 64;
    const int wn = (wave & 1) * 64;
    const int lm = lane & 31;
    const int hi = lane >> 5;
    const int key = (lm >> 1) & 3;
    const int sw0 = ((0 + hi) ^ key) * 8;
    const int sw1 = ((2 + hi) ^ key) * 8;

    floatx16 ac[2][2];
#pragma unroll
    for (int i = 0; i < 2; ++i)
#pragma unroll
        for (int j = 0; j < 2; ++j)
#pragma unroll
            for (int r = 0; r < 16; ++r) ac[i][j][r] = 0.f;

#define STAGE_D(B) do { u16* _s = smem + (B) * 8192 + ldsW;                   \
        GLOAD_LDS(pA0, _s);        GLOAD_LDS(pA1, _s + 512);                  \
        GLOAD_LDS(pB0, _s + 4096); GLOAD_LDS(pB1, _s + 4608);                 \
        pA0 += 32; pA1 += 32; pB0 += 32; pB1 += 32; } while (0)

#define COMPUTE_D(B) do {                                                     \
        const u16* _A = smem + (B) * 8192;                                    \
        const u16* _B = _A + 4096;                                            \
        _Pragma("unroll")                                                     \
        for (int ks = 0; ks < 2; ++ks) {                                      \
            const int sw = ks ? sw1 : sw0;                                    \
            bf16x8 a[2], b[2];                                                \
            _Pragma("unroll")                                                 \
            for (int i = 0; i < 2; ++i) {                                     \
                a[i] = *(const bf16x8*)(_A + (wm + i * 32 + lm) * 32 + sw);   \
                b[i] = *(const bf16x8*)(_B + (wn + i * 32 + lm) * 32 + sw);   \
            }                                                                 \
            _Pragma("unroll")                                                 \
            for (int i = 0; i < 2; ++i)                                       \
                _Pragma("unroll")                                             \
                for (int j = 0; j < 2; ++j)                                   \
                    ac[i][j] = __builtin_amdgcn_mfma_f32_32x32x16_bf16(a[i], b[j], ac[i][j], 0, 0, 0); \
        } } while (0)

    STAGE_D(0);
    __syncthreads();
#pragma unroll 1
    for (int it = 0; it < INTER / 32; it += 2) {
        STAGE_D(1);
        COMPUTE_D(0);
        __syncthreads();
        if (it + 2 < INTER / 32) STAGE_D(0);
        COMPUTE_D(1);
        __syncthreads();
    }
#undef STAGE_D
#undef COMPUTE_D

    const int rb = 4 * hi;
#pragma unroll
    for (int i = 0; i < 2; ++i)
#pragma unroll
        for (int j = 0; j < 2; ++j)
#pragma unroll
            for (int r = 0; r < 16; ++r) {
                int rr = wm + i * 32 + rb + (r & 3) + 8 * (r >> 2);
                int cc = wn + j * 32 + lm;
                out[(size_t)(row0 + rr) * HIDDEN + (col0 + cc)] = ac[i][j][r];
            }
}

extern "C" void kernel_launch(void* const* d_in, const int* in_sizes, int n_in,
                              void* d_out, int out_size, void* d_ws, size_t ws_size,
                              hipStream_t stream) {
    const float* x  = (const float*)d_in[0];
    const float* wg = (const float*)d_in[1];
    const float* wu = (const float*)d_in[2];
    const float* wd = (const float*)d_in[3];
    const int*  gsz = (const int*)d_in[4];
    float* out = (float*)d_out;

    // workspace layout (bf16 buffers), total ~480 MiB
    const size_t XB_BYTES = (size_t)TOKENS * HIDDEN * 2;
    const size_t W_BYTES  = (size_t)NEXP * HIDDEN * INTER * 2;
    char* ws = (char*)d_ws;
    u16* xb   = (u16*)(ws);
    u16* wgb  = (u16*)(ws + XB_BYTES);
    u16* wub  = (u16*)(ws + XB_BYTES + W_BYTES);
    u16* wdb  = (u16*)(ws + XB_BYTES + 2 * W_BYTES);
    u16* hbuf = (u16*)(ws + XB_BYTES + 3 * W_BYTES);

    convert_x<<<(TOKENS * HIDDEN) / (4 * 256), 256, 0, stream>>>(x, xb);

    dim3 tg(INTER / 64, HIDDEN / 64, NEXP);   // w_gate/w_up: [E][H][I] -> [E][I][H]
    transpose_cvt<<<tg, 256, 0, stream>>>(wg, wgb, HIDDEN, INTER);
    transpose_cvt<<<tg, 256, 0, stream>>>(wu, wub, HIDDEN, INTER);
    dim3 td(HIDDEN / 64, INTER / 64, NEXP);   // w_down: [E][I][H] -> [E][H][I]
    transpose_cvt<<<td, 256, 0, stream>>>(wd, wdb, INTER, HIDDEN);

    gemm_gateup<<<256 * (INTER / 128), 256, 0, stream>>>(xb, wgb, wub, gsz, hbuf);
    gemm_down<<<256 * (HIDDEN / 128), 256, 0, stream>>>(hbuf, wdb, gsz, out);
}